// Round 5
// baseline (229.736 us; speedup 1.0000x reference)
//
#include <hip/hip_runtime.h>
#include <math.h>

// PLIF forward: x[B,T,C,H,W] fp32, tau[C] fp32 -> spikes[B,T,C,H,W] fp32
// Per-site sequential scan over T with leak sigma(tau[c]) and hard reset.
// Loads: normal/cached (x may be L3-resident from the harness's restore copy).
// Stores: nontemporal (out is write-once, never re-read in the timed window;
// keep it from evicting x out of Infinity Cache).
typedef float fx4 __attribute__((ext_vector_type(4)));

constexpr int Bn = 32, Tn = 8, Cn = 128, Hn = 32, Wn = 32;
constexpr int HWv  = Hn * Wn;        // 1024
constexpr int CHW  = Cn * HWv;       // 131072
constexpr int CHW4 = CHW / 4;        // 32768  (fx4 units)
constexpr int NV4  = Bn * CHW4;      // 1048576 threads total

__global__ __launch_bounds__(256) void plif_fwd(const float* __restrict__ x,
                                                const float* __restrict__ tau,
                                                float* __restrict__ out) {
    int i4 = blockIdx.x * blockDim.x + threadIdx.x;   // index over [B, CHW/4]
    int b    = i4 >> 15;             // / CHW4
    int chw4 = i4 & (CHW4 - 1);
    int c    = chw4 >> 8;            // (chw4*4) / HW  (HW=1024)

    // sigma(tau[c]); tau==0 -> exactly 0.5, so the mem-chain below is
    // bitwise-identical to numpy regardless of FMA contraction.
    float ts = 1.0f / (1.0f + expf(-tau[c]));

    const fx4* xv = (const fx4*)x;
    fx4*       ov = (fx4*)out;
    int base = b * Tn * CHW4 + chw4; // max index 8,388,607 < 2^31: int is safe

    // Issue all 8 t-loads up front (independent addresses -> full MLP).
    // Cached: restore-copy likely left x resident in L2/LLC.
    fx4 v[Tn];
#pragma unroll
    for (int t = 0; t < Tn; ++t) v[t] = xv[base + t * CHW4];

    // Sequential membrane scan; forbid contraction so semantics = mul-then-add.
    float m0 = 0.f, m1 = 0.f, m2 = 0.f, m3 = 0.f;
#pragma unroll
    for (int t = 0; t < Tn; ++t) {
        m0 = __fadd_rn(__fmul_rn(m0, ts), v[t].x);
        m1 = __fadd_rn(__fmul_rn(m1, ts), v[t].y);
        m2 = __fadd_rn(__fmul_rn(m2, ts), v[t].z);
        m3 = __fadd_rn(__fmul_rn(m3, ts), v[t].w);
        fx4 s;
        s.x = (__fadd_rn(m0, -1.0f) > 0.0f) ? 1.0f : 0.0f;
        s.y = (__fadd_rn(m1, -1.0f) > 0.0f) ? 1.0f : 0.0f;
        s.z = (__fadd_rn(m2, -1.0f) > 0.0f) ? 1.0f : 0.0f;
        s.w = (__fadd_rn(m3, -1.0f) > 0.0f) ? 1.0f : 0.0f;
        m0 = (s.x > 0.f) ? 0.f : m0;   // hard reset
        m1 = (s.y > 0.f) ? 0.f : m1;
        m2 = (s.z > 0.f) ? 0.f : m2;
        m3 = (s.w > 0.f) ? 0.f : m3;
        __builtin_nontemporal_store(s, &ov[base + t * CHW4]);
    }
}

extern "C" void kernel_launch(void* const* d_in, const int* in_sizes, int n_in,
                              void* d_out, int out_size, void* d_ws, size_t ws_size,
                              hipStream_t stream) {
    const float* x   = (const float*)d_in[0];
    const float* tau = (const float*)d_in[1];
    float*       out = (float*)d_out;
    dim3 block(256);
    dim3 grid(NV4 / 256);   // 4096 blocks, exact cover
    plif_fwd<<<grid, block, 0, stream>>>(x, tau, out);
}

// Round 7
// 225.958 us; speedup vs baseline: 1.0167x; 1.0167x over previous
//
#include <hip/hip_runtime.h>
#include <math.h>

// PLIF forward: x[B,T,C,H,W] fp32, tau[C] fp32 -> spikes[B,T,C,H,W] fp32
// Streaming, zero-reuse -> nontemporal loads AND stores (measured best, R4 vs
// R2/R5 A/B). Each thread processes TWO (b, chw4) columns (b and b+16) for
// 16 in-flight loads and two independent scan chains.
typedef float fx4 __attribute__((ext_vector_type(4)));

constexpr int Bn = 32, Tn = 8, Cn = 128, Hn = 32, Wn = 32;
constexpr int HWv   = Hn * Wn;        // 1024
constexpr int CHW   = Cn * HWv;       // 131072
constexpr int CHW4  = CHW / 4;        // 32768  (fx4 units)
constexpr int NV4   = Bn * CHW4;      // 1048576 fx4 elements total
constexpr int NTHR  = NV4 / 2;        // 524288 threads (2 columns each)

__global__ __launch_bounds__(256) void plif_fwd(const float* __restrict__ x,
                                                const float* __restrict__ tau,
                                                float* __restrict__ out) {
    int i4 = blockIdx.x * blockDim.x + threadIdx.x;   // [0, NTHR)
    int b    = i4 >> 15;             // 0..15  (second column uses b+16)
    int chw4 = i4 & (CHW4 - 1);
    int c    = chw4 >> 8;            // (chw4*4) / HW  (HW=1024)

    // sigma(tau[c]); tau==0 -> exactly 0.5, so the mem-chain below is
    // bitwise-identical to numpy regardless of FMA contraction.
    float ts = 1.0f / (1.0f + expf(-tau[c]));

    const fx4* xv = (const fx4*)x;
    fx4*       ov = (fx4*)out;
    int base0 = b * Tn * CHW4 + chw4;
    int base1 = (b + 16) * Tn * CHW4 + chw4;   // max < 2^23, int safe

    // 16 independent nontemporal loads in flight.
    fx4 va[Tn], vb[Tn];
#pragma unroll
    for (int t = 0; t < Tn; ++t) va[t] = __builtin_nontemporal_load(&xv[base0 + t * CHW4]);
#pragma unroll
    for (int t = 0; t < Tn; ++t) vb[t] = __builtin_nontemporal_load(&xv[base1 + t * CHW4]);

    // Two independent sequential membrane scans; no contraction (mul-then-add
    // semantics identical to numpy; exact anyway for ts=0.5).
    float m0 = 0.f, m1 = 0.f, m2 = 0.f, m3 = 0.f;
    float n0 = 0.f, n1 = 0.f, n2 = 0.f, n3 = 0.f;
#pragma unroll
    for (int t = 0; t < Tn; ++t) {
        m0 = __fadd_rn(__fmul_rn(m0, ts), va[t].x);
        m1 = __fadd_rn(__fmul_rn(m1, ts), va[t].y);
        m2 = __fadd_rn(__fmul_rn(m2, ts), va[t].z);
        m3 = __fadd_rn(__fmul_rn(m3, ts), va[t].w);
        n0 = __fadd_rn(__fmul_rn(n0, ts), vb[t].x);
        n1 = __fadd_rn(__fmul_rn(n1, ts), vb[t].y);
        n2 = __fadd_rn(__fmul_rn(n2, ts), vb[t].z);
        n3 = __fadd_rn(__fmul_rn(n3, ts), vb[t].w);
        fx4 sa, sb;
        sa.x = (m0 > 1.0f) ? 1.0f : 0.0f;   // (m-1)>0  <=>  m>1, exact
        sa.y = (m1 > 1.0f) ? 1.0f : 0.0f;
        sa.z = (m2 > 1.0f) ? 1.0f : 0.0f;
        sa.w = (m3 > 1.0f) ? 1.0f : 0.0f;
        sb.x = (n0 > 1.0f) ? 1.0f : 0.0f;
        sb.y = (n1 > 1.0f) ? 1.0f : 0.0f;
        sb.z = (n2 > 1.0f) ? 1.0f : 0.0f;
        sb.w = (n3 > 1.0f) ? 1.0f : 0.0f;
        m0 = (sa.x > 0.f) ? 0.f : m0;  m1 = (sa.y > 0.f) ? 0.f : m1;
        m2 = (sa.z > 0.f) ? 0.f : m2;  m3 = (sa.w > 0.f) ? 0.f : m3;
        n0 = (sb.x > 0.f) ? 0.f : n0;  n1 = (sb.y > 0.f) ? 0.f : n1;
        n2 = (sb.z > 0.f) ? 0.f : n2;  n3 = (sb.w > 0.f) ? 0.f : n3;
        __builtin_nontemporal_store(sa, &ov[base0 + t * CHW4]);
        __builtin_nontemporal_store(sb, &ov[base1 + t * CHW4]);
    }
}

extern "C" void kernel_launch(void* const* d_in, const int* in_sizes, int n_in,
                              void* d_out, int out_size, void* d_ws, size_t ws_size,
                              hipStream_t stream) {
    const float* x   = (const float*)d_in[0];
    const float* tau = (const float*)d_in[1];
    float*       out = (float*)d_out;
    dim3 block(256);
    dim3 grid(NTHR / 256);   // 2048 blocks, exact cover
    plif_fwd<<<grid, block, 0, stream>>>(x, tau, out);
}